// Round 9
// baseline (491.483 us; speedup 1.0000x reference)
//
#include <hip/hip_runtime.h>
#include <hip/hip_fp16.h>

// Problem constants (from reference)
#define FDIM 512
#define TDK  0.1f   // TIME_DECAY
#define DTs  0.2f   // DIFF_T / NUM_STEPS
#define EPSv 1e-5f

using bf16x8  = __attribute__((ext_vector_type(8))) __bf16;
using floatx4 = __attribute__((ext_vector_type(4))) float;
using ushort8 = __attribute__((ext_vector_type(8))) unsigned short;
using uintx4  = __attribute__((ext_vector_type(4))) unsigned int;   // native vec for nontemporal builtins

__device__ __forceinline__ unsigned short f2bf(float f) {
  unsigned int u = __float_as_uint(f);
  u += 0x7fffu + ((u >> 16) & 1u);   // RNE
  return (unsigned short)(u >> 16);
}

// async global->LDS, 16 B per lane; LDS dest = wave-uniform base + lane*16
__device__ __forceinline__ void gld16(const __bf16* g, __bf16* l) {
  __builtin_amdgcn_global_load_lds(
      (const __attribute__((address_space(1))) unsigned int*)g,
      (__attribute__((address_space(3))) unsigned int*)l, 16, 0, 0);
}

// ---- per-edge decay weight + PACKED (count|deg) atomic ----------------------
// ts.max() eliminated: ew = dinv[s]*w*dinv[d] is invariant to the uniform
// factor exp(-TDK*tm) (cancels between w and the two dinv terms) -> condition
// on graph_time: w = exp(TDK*(t - gt)) <= 1.
// ONE 64-bit atomic replaces two 4B atomics: bits 52+ = count, bits 0..51 =
// fixed-point sum of w*2^32 (max deg ~60; quantization ~1e-9 relative).
__global__ __launch_bounds__(256) void edge_w_deg(const int* __restrict__ src, const int* __restrict__ dst,
                                                  const float* __restrict__ ts, const int* __restrict__ gt_p,
                                                  float* __restrict__ w, unsigned long long* __restrict__ pc,
                                                  int E, int N) {
  int e = blockIdx.x * blockDim.x + threadIdx.x;
  int total = E + N;
  if (e >= total) return;
  float gtf = (float)(*gt_p);
  int d; float t;
  if (e < E) { d = dst[e]; t = ts[e]; }
  else       { d = e - E;  t = gtf; }
  float wv = expf(TDK * (t - gtf));
  w[e] = wv;
  unsigned long long pk = (1ULL << 52) + (unsigned long long)(wv * 4294967296.0f);
  atomicAdd(&pc[d], pk);
}

// ---- parallel 3-phase scan over packed counts -------------------------------
__global__ __launch_bounds__(256) void seg_reduce(const unsigned long long* __restrict__ pc,
                                                  int* __restrict__ bsum, int n) {
  int i = blockIdx.x * 256 + threadIdx.x;
  int v = (i < n) ? (int)(pc[i] >> 52) : 0;
  for (int o = 32; o; o >>= 1) v += __shfl_down(v, o);
  __shared__ int sm[4];
  if ((threadIdx.x & 63) == 0) sm[threadIdx.x >> 6] = v;
  __syncthreads();
  if (threadIdx.x == 0) bsum[blockIdx.x] = sm[0] + sm[1] + sm[2] + sm[3];
}

__global__ __launch_bounds__(256) void scan_bsum(const int* __restrict__ bsum, int* __restrict__ bbase, int nb) {
  __shared__ int sm[256];
  int t = threadIdx.x;
  int v = (t < nb) ? bsum[t] : 0;
  sm[t] = v;
  __syncthreads();
  for (int o = 1; o < 256; o <<= 1) {
    int u = (t >= o) ? sm[t - o] : 0;
    __syncthreads();
    sm[t] += u;
    __syncthreads();
  }
  if (t < nb) bbase[t] = sm[t] - v;   // exclusive
}

// seg_scan + dinv + cursor init fused (dinv unpacked from the fixed-point deg)
__global__ __launch_bounds__(256) void seg_scan(const unsigned long long* __restrict__ pc,
                                                const int* __restrict__ bbase,
                                                int* __restrict__ offs, int* __restrict__ cursor,
                                                float* __restrict__ dinv, int n, int totE) {
  __shared__ int sm[256];
  int i = blockIdx.x * 256 + threadIdx.x;
  unsigned long long p = (i < n) ? pc[i] : 0ULL;
  int v = (int)(p >> 52);
  sm[threadIdx.x] = v;
  __syncthreads();
  for (int o = 1; o < 256; o <<= 1) {
    int u = (threadIdx.x >= o) ? sm[threadIdx.x - o] : 0;
    __syncthreads();
    sm[threadIdx.x] += u;
    __syncthreads();
  }
  int excl = sm[threadIdx.x] - v + bbase[blockIdx.x];
  if (i < n) {
    offs[i] = excl; cursor[i] = excl;
    float deg = (float)(p & ((1ULL << 52) - 1ULL)) * (1.0f / 4294967296.0f);
    dinv[i] = (deg > 0.f) ? rsqrtf(deg) : 0.f;
  }
  if (i == 0) offs[n] = totE;
}

// -- scatter edges into CSR, packed 4 B: lo16 = src (N<65536), hi16 = fp16 val -
__global__ __launch_bounds__(256) void scatter_kernel(const int* __restrict__ src, const int* __restrict__ dst,
                                                      const float* __restrict__ w, const float* __restrict__ dinv,
                                                      int* __restrict__ cursor, unsigned* __restrict__ cv,
                                                      int E, int N) {
  int e = blockIdx.x * blockDim.x + threadIdx.x;
  if (e >= E + N) return;
  int s, d;
  if (e < E) { s = src[e]; d = dst[e]; }
  else       { s = d = e - E; }
  int pos = atomicAdd(&cursor[d], 1);
  float v = dinv[s] * w[e] * dinv[d];
  unsigned short hv = __half_as_ushort(__float2half(v));
  cv[pos] = (unsigned)s | ((unsigned)hv << 16);
}

// ---- one diffusion step: ONE ROW PER WAVE (divergence-free) -----------------
// r9 experiment. Old structure: 8 independent rows per wave, each walked by an
// 8-lane group -> wave loop iterates to the MAX of 8 trip counts (exec-masked),
// ~1.7x issue waste at deg~Poisson(17). New: 64 lanes = 8 edges x 8 lanes/edge,
// all lanes share ONE row -> loop bounds wave-uniform (scalar branch, zero
// masking waste). 16 edges per full iter (2 gathers in flight/lane) + 8-edge
// step + one masked tail. Gather pattern per inst is IDENTICAL (8 random 128B
// segments); cv load improves (1 coalesced 32B load vs 8 broadcast loads).
// One-time butterfly reduce (24 shfl_xor over edge-slots) sits OUTSIDE the
// gather chain (r2's in-chain-shfl lesson doesn't apply). 160K waves at ~40
// VGPR -> full TLP. chunk = blockIdx&7 -> XCD-affine slab (L2-resident).
// Do NOT: shfl cv in-chain (r2), nt cv (r2), 16-deep per-lane batch (r6).
__device__ __forceinline__ void acc8(uintx4 u, float v, float* a) {
  a[0] += v * __uint_as_float(u[0] << 16);
  a[1] += v * __uint_as_float(u[0] & 0xffff0000u);
  a[2] += v * __uint_as_float(u[1] << 16);
  a[3] += v * __uint_as_float(u[1] & 0xffff0000u);
  a[4] += v * __uint_as_float(u[2] << 16);
  a[5] += v * __uint_as_float(u[2] & 0xffff0000u);
  a[6] += v * __uint_as_float(u[3] << 16);
  a[7] += v * __uint_as_float(u[3] & 0xffff0000u);
}

__device__ __forceinline__ float cvval(unsigned cu) {
  return __half2float(__ushort_as_half((unsigned short)(cu >> 16)));
}

__global__ __launch_bounds__(256) void spmm_xcd(const int* __restrict__ offs, const unsigned* __restrict__ cv,
                                                const unsigned short* __restrict__ h_in,
                                                unsigned short* __restrict__ h_out, int N) {
  int chunk  = blockIdx.x & 7;
  int rowblk = blockIdx.x >> 3;
  int wid = threadIdx.x >> 6, lane = threadIdx.x & 63;
  int row = rowblk * 4 + wid;
  if (row >= N) return;
  int es = lane >> 3;                  // edge slot 0..7
  int l7 = lane & 7;                   // 16B slice within the 128B row-chunk
  int fo = chunk * 64 + l7 * 8;
  const unsigned short* hp = h_in + fo;
  int s = offs[row], e = offs[row + 1];
  float a[8] = {0.f, 0.f, 0.f, 0.f, 0.f, 0.f, 0.f, 0.f};
  int j = s;
  // full 16-edge iterations: wave-uniform bounds, no masking, 2 gathers/lane
  for (; j + 16 <= e; j += 16) {
    unsigned c0 = cv[j + es];
    unsigned c1 = cv[j + 8 + es];
    uintx4 u0 = *(const uintx4*)(hp + ((c0 & 0xffffu) << 9));
    uintx4 u1 = *(const uintx4*)(hp + ((c1 & 0xffffu) << 9));
    acc8(u0, cvval(c0), a);
    acc8(u1, cvval(c1), a);
  }
  if (j + 8 <= e) {                    // full 8-edge step
    unsigned c0 = cv[j + es];
    uintx4 u0 = *(const uintx4*)(hp + ((c0 & 0xffffu) << 9));
    acc8(u0, cvval(c0), a);
    j += 8;
  }
  if (j < e) {                         // masked tail (1..7 edges)
    int idx = j + es;
    unsigned c0 = 0;
    uintx4 u0; u0[0] = 0; u0[1] = 0; u0[2] = 0; u0[3] = 0;
    if (idx < e) {
      c0 = cv[idx];
      u0 = *(const uintx4*)(hp + ((c0 & 0xffffu) << 9));
    }
    acc8(u0, cvval(c0), a);            // masked lanes: 0 * 0 = 0
  }
  // butterfly reduce across edge slots (lanes differing in bits 3..5)
#pragma unroll
  for (int o = 8; o <= 32; o <<= 1) {
#pragma unroll
    for (int k = 0; k < 8; ++k) a[k] += __shfl_xor(a[k], o);
  }
  // self term + pack + nontemporal store (one 8-lane slice writes the 128B)
  if (es == 0) {
    uintx4 ud = *(const uintx4*)(hp + (row << 9));
    float hd[8];
    hd[0] = __uint_as_float(ud[0] << 16); hd[1] = __uint_as_float(ud[0] & 0xffff0000u);
    hd[2] = __uint_as_float(ud[1] << 16); hd[3] = __uint_as_float(ud[1] & 0xffff0000u);
    hd[4] = __uint_as_float(ud[2] << 16); hd[5] = __uint_as_float(ud[2] & 0xffff0000u);
    hd[6] = __uint_as_float(ud[3] << 16); hd[7] = __uint_as_float(ud[3] & 0xffff0000u);
    uintx4 o;
    unsigned int p0, p1;
#define PACK(k0, k1, dst_)                                        \
    { float o0 = hd[k0] + DTs * (a[k0] - hd[k0]);                 \
      float o1 = hd[k1] + DTs * (a[k1] - hd[k1]);                 \
      p0 = f2bf(o0); p1 = f2bf(o1); dst_ = p0 | (p1 << 16); }
    PACK(0, 1, o[0]) PACK(2, 3, o[1]) PACK(4, 5, o[2]) PACK(6, 7, o[3])
#undef PACK
    __builtin_nontemporal_store(o, (uintx4*)(h_out + (size_t)row * FDIM + fo));
  }
}

// ------------- fp32 -> bf16 cast, all three arrays in ONE launch --------------
__global__ __launch_bounds__(256) void cast_all(const float* __restrict__ x, const float* __restrict__ wt,
                                                const float* __restrict__ wr,
                                                unsigned short* __restrict__ xb, unsigned short* __restrict__ wtb,
                                                unsigned short* __restrict__ wrb, int n8x, int n8w) {
  int i = blockIdx.x * blockDim.x + threadIdx.x;
  const float* sp; unsigned short* dp; int k;
  if (i < n8x)                { sp = x;  dp = xb;  k = i; }
  else if (i < n8x + n8w)     { sp = wt; dp = wtb; k = i - n8x; }
  else if (i < n8x + 2 * n8w) { sp = wr; dp = wrb; k = i - n8x - n8w; }
  else return;
  const float4 v0 = *(const float4*)(sp + (size_t)k * 8);
  const float4 v1 = *(const float4*)(sp + (size_t)k * 8 + 4);
  ushort8 o;
  o[0] = f2bf(v0.x); o[1] = f2bf(v0.y); o[2] = f2bf(v0.z); o[3] = f2bf(v0.w);
  o[4] = f2bf(v1.x); o[5] = f2bf(v1.y); o[6] = f2bf(v1.z); o[7] = f2bf(v1.w);
  *(ushort8*)(dp + (size_t)k * 8) = o;
}

// --- fused dual GEMM, SEQUENTIAL two-phase, double-buffered async-LDS --------
// out = relu(Ah @ Wt^T + bias) + Ax @ Wr^T
// r1 configuration -- measured best of this structure (40.3 us): tile 128x128,
// BK=32, 4 waves 2x2, LDS 32 KB, grid 628 + bijective XCD swizzle. Knob record:
// 64x128 = 42.6 (r4), BK=64/48KB = 48.3 (r5). 2-barrier vmcnt(0) loop plateaus
// ~40 us (m97-structure ceiling); N=512 too narrow for 8-phase 256^2. FROZEN.
__global__ __launch_bounds__(256, 3) void gemm_fused(const __bf16* __restrict__ Ah, const __bf16* __restrict__ Ax,
                                                     const __bf16* __restrict__ Wt, const __bf16* __restrict__ Wr,
                                                     const float* __restrict__ bias, float* __restrict__ out,
                                                     int M, int NB) {
  __shared__ __bf16 sA[2][128 * 32];
  __shared__ __bf16 sB[2][128 * 32];
  int tid = threadIdx.x;
  int wid = tid >> 6, lane = tid & 63;
  int wm = wid & 1, wn = wid >> 1;
  int lane15 = lane & 15, quad = lane >> 4;

  // bijective XCD swizzle (works for NB % 8 != 0): d%8 = XCD, d/8 = slot;
  // XCD x covers g in a contiguous range -> mi runs contiguous, ni = g&3.
  int d = blockIdx.x;
  int x = d & 7, s = d >> 3;
  int q = NB >> 3, r = NB & 7;
  int g = (x < r ? x * (q + 1) : r * (q + 1) + (x - r) * q) + s;
  int mi = g >> 2, ni = g & 3;
  int m0 = mi * 128, n0 = ni * 128;

  // staging: wave covers rows [wid*32, wid*32+32), 2 instrs of 16 rows each.
  // lane -> row wid*32 + lane/4 (+16), swizzled k-segment ((lane&3)-(lane>>3))&3
  int r0 = wid * 32 + (lane >> 2);
  int c0 = ((((lane & 3) - (lane >> 3)) & 3)) * 8;   // swizzled element offset
  int am0 = m0 + r0;      if (am0 >= M) am0 = M - 1;
  int am1 = m0 + r0 + 16; if (am1 >= M) am1 = M - 1;
  int bn0 = n0 + r0;                                 // N dim = 512, full tiles
  const __bf16* a00 = Ah + (size_t)am0 * FDIM + c0;  // phase-1 A
  const __bf16* a01 = Ah + (size_t)am1 * FDIM + c0;
  const __bf16* a10 = Ax + (size_t)am0 * FDIM + c0;  // phase-2 A
  const __bf16* a11 = Ax + (size_t)am1 * FDIM + c0;
  const __bf16* b00 = Wt + (size_t)bn0 * FDIM + c0;  // phase-1 B
  const __bf16* b01 = Wt + (size_t)(bn0 + 16) * FDIM + c0;
  const __bf16* b10 = Wr + (size_t)bn0 * FDIM + c0;  // phase-2 B
  const __bf16* b11 = Wr + (size_t)(bn0 + 16) * FDIM + c0;
  int loff0 = wid * 1024;          // (wid*32 rows) * 32 elems
  int loff1 = wid * 1024 + 512;    // +16 rows

  auto stage = [&](int b, const __bf16* pa0, const __bf16* pa1,
                   const __bf16* pb0, const __bf16* pb1, int kt) {
    gld16(pa0 + kt, &sA[b][loff0]); gld16(pa1 + kt, &sA[b][loff1]);
    gld16(pb0 + kt, &sB[b][loff0]); gld16(pb1 + kt, &sB[b][loff1]);
  };

  // read-side swizzled k offset: slot = (quad + (row>>1)) & 3
  int koff = ((quad + (lane15 >> 1)) & 3) * 8;

  // bias for this wave's 4 n-fragments (needed at the phase transition)
  float bn[4];
#pragma unroll
  for (int in = 0; in < 4; ++in) bn[in] = bias[n0 + wn * 64 + in * 16 + lane15];

  floatx4 acc[4][4];
  floatx4 z4; z4[0] = 0.f; z4[1] = 0.f; z4[2] = 0.f; z4[3] = 0.f;
#pragma unroll
  for (int im = 0; im < 4; ++im)
#pragma unroll
    for (int in = 0; in < 4; ++in) acc[im][in] = z4;

  stage(0, a00, a01, b00, b01, 0);
  for (int it = 0; it < 32; ++it) {
    int cb = it & 1;
    __syncthreads();                       // staging of buf cb complete; prior reads of buf 1-cb done
    int nx = it + 1;
    if (nx < 32) {
      if (nx < 16) stage(1 - cb, a00, a01, b00, b01, nx * 32);
      else         stage(1 - cb, a10, a11, b10, b11, (nx & 15) * 32);
    }
    if (it == 16) {                        // phase transition: relu(acc + bias), in registers
#pragma unroll
      for (int im = 0; im < 4; ++im)
#pragma unroll
        for (int in = 0; in < 4; ++in)
#pragma unroll
          for (int rr = 0; rr < 4; ++rr)
            acc[im][in][rr] = fmaxf(acc[im][in][rr] + bn[in], 0.f);
    }
    bf16x8 af[4], br[4];
#pragma unroll
    for (int im = 0; im < 4; ++im)
      af[im] = *(const bf16x8*)(&sA[cb][(wm * 64 + im * 16 + lane15) * 32 + koff]);
#pragma unroll
    for (int in = 0; in < 4; ++in)
      br[in] = *(const bf16x8*)(&sB[cb][(wn * 64 + in * 16 + lane15) * 32 + koff]);
#pragma unroll
    for (int im = 0; im < 4; ++im)
#pragma unroll
      for (int in = 0; in < 4; ++in)
        acc[im][in] = __builtin_amdgcn_mfma_f32_16x16x32_bf16(af[im], br[in], acc[im][in], 0, 0, 0);
  }

  // epilogue: C/D layout col=lane&15, row=quad*4+reg
#pragma unroll
  for (int im = 0; im < 4; ++im) {
#pragma unroll
    for (int in = 0; in < 4; ++in) {
#pragma unroll
      for (int rr = 0; rr < 4; ++rr) {
        int m = m0 + wm * 64 + im * 16 + quad * 4 + rr;
        int n = n0 + wn * 64 + in * 16 + lane15;
        if (m < M) out[(size_t)m * FDIM + n] = acc[im][in][rr];
      }
    }
  }
}

// ------------------------------ rowwise LayerNorm -----------------------------
__global__ __launch_bounds__(256) void ln_kernel(const float* __restrict__ pre, const float* __restrict__ gamma,
                                                 const float* __restrict__ beta, float* __restrict__ out) {
  int row = blockIdx.x, t = threadIdx.x;
  float2 v = *(const float2*)(pre + (size_t)row * FDIM + t * 2);
  float s = v.x + v.y;
  float ss = v.x * v.x + v.y * v.y;
  for (int off = 32; off; off >>= 1) { s += __shfl_down(s, off); ss += __shfl_down(ss, off); }
  __shared__ float sm[4], sm2[4];
  int wid = t >> 6, lane = t & 63;
  if (lane == 0) { sm[wid] = s; sm2[wid] = ss; }
  __syncthreads();
  if (t == 0) {
    float a = sm[0] + sm[1] + sm[2] + sm[3];
    float b = sm2[0] + sm2[1] + sm2[2] + sm2[3];
    sm[0] = a; sm2[0] = b;
  }
  __syncthreads();
  float mu = sm[0] * (1.f / FDIM);
  float var = sm2[0] * (1.f / FDIM) - mu * mu;
  float inv = rsqrtf(var + EPSv);
  float2 g  = *(const float2*)(gamma + t * 2);
  float2 bb = *(const float2*)(beta + t * 2);
  float2 o;
  o.x = (v.x - mu) * inv * g.x + bb.x;
  o.y = (v.y - mu) * inv * g.y + bb.y;
  *(float2*)(out + (size_t)row * FDIM + t * 2) = o;
}

extern "C" void kernel_launch(void* const* d_in, const int* in_sizes, int n_in,
                              void* d_out, int out_size, void* d_ws, size_t ws_size,
                              hipStream_t stream) {
  const float* x     = (const float*)d_in[0];
  const int*   ei    = (const int*)d_in[1];
  const float* ts    = (const float*)d_in[2];
  const float* W_t   = (const float*)d_in[3];
  const float* b_t   = (const float*)d_in[4];
  const float* W_r   = (const float*)d_in[5];
  const float* gamma = (const float*)d_in[6];
  const float* beta  = (const float*)d_in[7];
  const int*   gt    = (const int*)d_in[8];

  const int E = in_sizes[2];
  const int N = in_sizes[0] / FDIM;
  const int* src = ei;
  const int* dst = ei + E;
  const int totE = E + N;
  const int nb = (N + 255) / 256;   // scan segments (N=20000 -> 79 <= 256)

  // ---- workspace carve (all regions fully rewritten every call) ----
  char* base = (char*)d_ws;
  size_t off = 0;
  auto carve = [&](size_t bytes) -> char* {
    char* r = base + off;
    off = (off + bytes + 255) & ~(size_t)255;
    return r;
  };
  unsigned long long* pc = (unsigned long long*)carve((size_t)N * 8);   // packed cnt|deg
  size_t zero_bytes = off;                       // only pc needs zeroing
  float* dinv  = (float*)carve((size_t)N * 4);
  int*   offs  = (int*)  carve((size_t)(N + 1) * 4);
  int*   cursor= (int*)  carve((size_t)N * 4);
  int*   bsum  = (int*)  carve((size_t)nb * 4);
  int*   bbase = (int*)  carve((size_t)nb * 4);
  float* w     = (float*)carve((size_t)totE * 4);
  unsigned* cv = (unsigned*)carve((size_t)totE * 4);
  unsigned short* xb  = (unsigned short*)carve((size_t)N * FDIM * 2);   // bf16(x)
  unsigned short* hba = (unsigned short*)carve((size_t)N * FDIM * 2);   // bf16 h ping
  unsigned short* hbb = (unsigned short*)carve((size_t)N * FDIM * 2);   // bf16 h pong
  unsigned short* wtb = (unsigned short*)carve((size_t)FDIM * FDIM * 2);
  unsigned short* wrb = (unsigned short*)carve((size_t)FDIM * FDIM * 2);
  float* preLN = (float*)carve((size_t)N * FDIM * 4);

  hipMemsetAsync(d_ws, 0, zero_bytes, stream);

  edge_w_deg<<<(totE + 255) / 256, 256, 0, stream>>>(src, dst, ts, gt, w, pc, E, N);
  seg_reduce<<<nb, 256, 0, stream>>>(pc, bsum, N);
  scan_bsum<<<1, 256, 0, stream>>>(bsum, bbase, nb);
  seg_scan<<<nb, 256, 0, stream>>>(pc, bbase, offs, cursor, dinv, N, totE);
  scatter_kernel<<<(totE + 255) / 256, 256, 0, stream>>>(src, dst, w, dinv, cursor, cv, E, N);

  // single fused cast launch: x, W_t, W_r -> bf16
  int n8x = N * FDIM / 8;
  int n8w = FDIM * FDIM / 8;
  int n8tot = n8x + 2 * n8w;
  cast_all<<<(n8tot + 255) / 256, 256, 0, stream>>>(x, W_t, W_r, xb, wtb, wrb, n8x, n8w);

  // 5 Euler steps on bf16 state; chunk = blockIdx&7 -> XCD-affine L2 residency
  // one row per wave: block = 4 waves = 4 rows; grid = ceil(N/4)*8
  int sgrid = ((N + 3) / 4) * 8;
  spmm_xcd<<<sgrid, 256, 0, stream>>>(offs, cv, xb,  hba, N);
  spmm_xcd<<<sgrid, 256, 0, stream>>>(offs, cv, hba, hbb, N);
  spmm_xcd<<<sgrid, 256, 0, stream>>>(offs, cv, hbb, hba, N);
  spmm_xcd<<<sgrid, 256, 0, stream>>>(offs, cv, hba, hbb, N);
  spmm_xcd<<<sgrid, 256, 0, stream>>>(offs, cv, hbb, hba, N);

  // fused: preLN = relu(h @ Wt^T + b_t) + x @ Wr^T  (two-phase, 1-D swizzled grid)
  int MB = (N + 127) / 128;
  int NBLK = MB * (FDIM / 128);
  gemm_fused<<<NBLK, 256, 0, stream>>>((const __bf16*)hba, (const __bf16*)xb,
                                       (const __bf16*)wtb, (const __bf16*)wrb,
                                       b_t, preLN, N, NBLK);

  ln_kernel<<<N, 256, 0, stream>>>(preLN, gamma, beta, (float*)d_out);
}

// Round 10
// 353.807 us; speedup vs baseline: 1.3891x; 1.3891x over previous
//
#include <hip/hip_runtime.h>
#include <hip/hip_fp16.h>

// Problem constants (from reference)
#define FDIM 512
#define TDK  0.1f   // TIME_DECAY
#define DTs  0.2f   // DIFF_T / NUM_STEPS
#define EPSv 1e-5f

using bf16x8  = __attribute__((ext_vector_type(8))) __bf16;
using floatx4 = __attribute__((ext_vector_type(4))) float;
using ushort8 = __attribute__((ext_vector_type(8))) unsigned short;
using uintx4  = __attribute__((ext_vector_type(4))) unsigned int;   // native vec for nontemporal builtins

__device__ __forceinline__ unsigned short f2bf(float f) {
  unsigned int u = __float_as_uint(f);
  u += 0x7fffu + ((u >> 16) & 1u);   // RNE
  return (unsigned short)(u >> 16);
}

// async global->LDS, 16 B per lane; LDS dest = wave-uniform base + lane*16
__device__ __forceinline__ void gld16(const __bf16* g, __bf16* l) {
  __builtin_amdgcn_global_load_lds(
      (const __attribute__((address_space(1))) unsigned int*)g,
      (__attribute__((address_space(3))) unsigned int*)l, 16, 0, 0);
}

// ---- per-edge decay weight + PACKED (count|deg) atomic ----------------------
// ts.max() eliminated: ew = dinv[s]*w*dinv[d] is invariant to the uniform
// factor exp(-TDK*tm) (cancels between w and the two dinv terms) -> condition
// on graph_time: w = exp(TDK*(t - gt)) <= 1.
// ONE 64-bit atomic replaces two 4B atomics: bits 52+ = count, bits 0..51 =
// fixed-point sum of w*2^32 (max deg ~60; quantization ~1e-9 relative).
__global__ __launch_bounds__(256) void edge_w_deg(const int* __restrict__ src, const int* __restrict__ dst,
                                                  const float* __restrict__ ts, const int* __restrict__ gt_p,
                                                  float* __restrict__ w, unsigned long long* __restrict__ pc,
                                                  int E, int N) {
  int e = blockIdx.x * blockDim.x + threadIdx.x;
  int total = E + N;
  if (e >= total) return;
  float gtf = (float)(*gt_p);
  int d; float t;
  if (e < E) { d = dst[e]; t = ts[e]; }
  else       { d = e - E;  t = gtf; }
  float wv = expf(TDK * (t - gtf));
  w[e] = wv;
  unsigned long long pk = (1ULL << 52) + (unsigned long long)(wv * 4294967296.0f);
  atomicAdd(&pc[d], pk);
}

// ---- parallel 3-phase scan over PADDED counts -------------------------------
// Row counts padded to a multiple of 4: offs built on (cnt+3)&~3. Pad slots in
// cv are pre-zeroed (cv=0 -> src=0, val=fp16(0): gathers row 0, contributes 0),
// so the spmm inner loop needs NO serial tail -- just 8-batches + one 4-batch.
__global__ __launch_bounds__(256) void seg_reduce(const unsigned long long* __restrict__ pc,
                                                  int* __restrict__ bsum, int n) {
  int i = blockIdx.x * 256 + threadIdx.x;
  int v = (i < n) ? (((int)(pc[i] >> 52) + 3) & ~3) : 0;
  for (int o = 32; o; o >>= 1) v += __shfl_down(v, o);
  __shared__ int sm[4];
  if ((threadIdx.x & 63) == 0) sm[threadIdx.x >> 6] = v;
  __syncthreads();
  if (threadIdx.x == 0) bsum[blockIdx.x] = sm[0] + sm[1] + sm[2] + sm[3];
}

__global__ __launch_bounds__(256) void scan_bsum(const int* __restrict__ bsum, int* __restrict__ bbase,
                                                 int* __restrict__ offsN, int nb) {
  __shared__ int sm[256];
  int t = threadIdx.x;
  int v = (t < nb) ? bsum[t] : 0;
  sm[t] = v;
  __syncthreads();
  for (int o = 1; o < 256; o <<= 1) {
    int u = (t >= o) ? sm[t - o] : 0;
    __syncthreads();
    sm[t] += u;
    __syncthreads();
  }
  if (t < nb) bbase[t] = sm[t] - v;   // exclusive
  if (t == nb - 1) offsN[0] = sm[t];  // total padded edge count -> offs[N]
}

// seg_scan + dinv + cursor init fused (dinv unpacked from the fixed-point deg)
__global__ __launch_bounds__(256) void seg_scan(const unsigned long long* __restrict__ pc,
                                                const int* __restrict__ bbase,
                                                int* __restrict__ offs, int* __restrict__ cursor,
                                                float* __restrict__ dinv, int n) {
  __shared__ int sm[256];
  int i = blockIdx.x * 256 + threadIdx.x;
  unsigned long long p = (i < n) ? pc[i] : 0ULL;
  int v = ((int)(p >> 52) + 3) & ~3;              // padded count
  sm[threadIdx.x] = v;
  __syncthreads();
  for (int o = 1; o < 256; o <<= 1) {
    int u = (threadIdx.x >= o) ? sm[threadIdx.x - o] : 0;
    __syncthreads();
    sm[threadIdx.x] += u;
    __syncthreads();
  }
  int excl = sm[threadIdx.x] - v + bbase[blockIdx.x];
  if (i < n) {
    offs[i] = excl; cursor[i] = excl;             // real edges fill from start
    float deg = (float)(p & ((1ULL << 52) - 1ULL)) * (1.0f / 4294967296.0f);
    dinv[i] = (deg > 0.f) ? rsqrtf(deg) : 0.f;
  }
}

// -- scatter edges into CSR, packed 4 B: lo16 = src (N<65536), hi16 = fp16 val -
__global__ __launch_bounds__(256) void scatter_kernel(const int* __restrict__ src, const int* __restrict__ dst,
                                                      const float* __restrict__ w, const float* __restrict__ dinv,
                                                      int* __restrict__ cursor, unsigned* __restrict__ cv,
                                                      int E, int N) {
  int e = blockIdx.x * blockDim.x + threadIdx.x;
  if (e >= E + N) return;
  int s, d;
  if (e < E) { s = src[e]; d = dst[e]; }
  else       { s = d = e - E; }
  int pos = atomicAdd(&cursor[d], 1);
  float v = dinv[s] * w[e] * dinv[d];
  unsigned short hv = __half_as_ushort(__float2half(v));
  cv[pos] = (unsigned)s | ((unsigned)hv << 16);
}

// ---- one diffusion step, bf16 state, XCD-AFFINE feature chunks --------------
// EXACT r1 structure (the measured best, ~32 us/step: one row per 8-lane group,
// 32 rows/block, grid 5008, 8-deep gather batch, ~40 VGPR -> 8 waves/SIMD),
// with the serial tail ELIMINATED by pad-to-4 edge lists: loop = 8-batches +
// at most one 4-batch. Pad slots gather row 0 with weight 0 (exact).
// Do NOT: shfl-broadcast cv (r2: +70%), nontemporal cv (r2), two rows/group
// (r3: +38%), 16-deep batch (r6: +8%, VGPR step), cv-prefetch while-loop
// (r7: +3%), one-row-per-wave (r9: +100%, 8x per-wave overhead, 1/4 MLP).
// chunk = blockIdx.x & 7 -> all of chunk c on one XCD; 2.56 MB slab L2-resident
// (FETCH ~= compulsory confirms). h_out nontemporal so writes don't evict slab.
__device__ __forceinline__ void acc8(uintx4 u, float v, float* a) {
  a[0] += v * __uint_as_float(u[0] << 16);
  a[1] += v * __uint_as_float(u[0] & 0xffff0000u);
  a[2] += v * __uint_as_float(u[1] << 16);
  a[3] += v * __uint_as_float(u[1] & 0xffff0000u);
  a[4] += v * __uint_as_float(u[2] << 16);
  a[5] += v * __uint_as_float(u[2] & 0xffff0000u);
  a[6] += v * __uint_as_float(u[3] << 16);
  a[7] += v * __uint_as_float(u[3] & 0xffff0000u);
}

__device__ __forceinline__ float cvval(unsigned cu) {
  return __half2float(__ushort_as_half((unsigned short)(cu >> 16)));
}

__global__ __launch_bounds__(256) void spmm_xcd(const int* __restrict__ offs, const unsigned* __restrict__ cv,
                                                const unsigned short* __restrict__ h_in,
                                                unsigned short* __restrict__ h_out, int N) {
  int chunk = blockIdx.x & 7;
  int tile  = blockIdx.x >> 3;
  int row = tile * 32 + (threadIdx.x >> 3);
  if (row >= N) return;
  int fo = chunk * 64 + (threadIdx.x & 7) * 8;   // 8 bf16 = 16 B per lane
  const unsigned short* hp = h_in + fo;
  int s = offs[row], e = offs[row + 1];
  float a[8] = {0.f, 0.f, 0.f, 0.f, 0.f, 0.f, 0.f, 0.f};
  int j = s;
  for (; j + 8 <= e; j += 8) {
    unsigned cu[8]; uintx4 u[8];
#pragma unroll
    for (int t = 0; t < 8; ++t) cu[t] = cv[j + t];
#pragma unroll
    for (int t = 0; t < 8; ++t) u[t] = *(const uintx4*)(hp + ((cu[t] & 0xffffu) << 9));
#pragma unroll
    for (int t = 0; t < 8; ++t) acc8(u[t], cvval(cu[t]), a);
  }
  if (j < e) {                          // padded: exactly 4 edges remain
    unsigned cu[4]; uintx4 u[4];
#pragma unroll
    for (int t = 0; t < 4; ++t) cu[t] = cv[j + t];
#pragma unroll
    for (int t = 0; t < 4; ++t) u[t] = *(const uintx4*)(hp + ((cu[t] & 0xffffu) << 9));
#pragma unroll
    for (int t = 0; t < 4; ++t) acc8(u[t], cvval(cu[t]), a);
  }
  // self term: h + dt*(Ah - h)
  uintx4 ud = *(const uintx4*)(hp + (row << 9));
  float hd[8];
  hd[0] = __uint_as_float(ud[0] << 16); hd[1] = __uint_as_float(ud[0] & 0xffff0000u);
  hd[2] = __uint_as_float(ud[1] << 16); hd[3] = __uint_as_float(ud[1] & 0xffff0000u);
  hd[4] = __uint_as_float(ud[2] << 16); hd[5] = __uint_as_float(ud[2] & 0xffff0000u);
  hd[6] = __uint_as_float(ud[3] << 16); hd[7] = __uint_as_float(ud[3] & 0xffff0000u);
  uintx4 o;
  unsigned int p0, p1;
#define PACK(k0, k1, dst_)                                        \
  { float o0 = hd[k0] + DTs * (a[k0] - hd[k0]);                   \
    float o1 = hd[k1] + DTs * (a[k1] - hd[k1]);                   \
    p0 = f2bf(o0); p1 = f2bf(o1); dst_ = p0 | (p1 << 16); }
  PACK(0, 1, o[0]) PACK(2, 3, o[1]) PACK(4, 5, o[2]) PACK(6, 7, o[3])
#undef PACK
  __builtin_nontemporal_store(o, (uintx4*)(h_out + (size_t)row * FDIM + fo));
}

// ------------- fp32 -> bf16 cast, all three arrays in ONE launch --------------
__global__ __launch_bounds__(256) void cast_all(const float* __restrict__ x, const float* __restrict__ wt,
                                                const float* __restrict__ wr,
                                                unsigned short* __restrict__ xb, unsigned short* __restrict__ wtb,
                                                unsigned short* __restrict__ wrb, int n8x, int n8w) {
  int i = blockIdx.x * blockDim.x + threadIdx.x;
  const float* sp; unsigned short* dp; int k;
  if (i < n8x)                { sp = x;  dp = xb;  k = i; }
  else if (i < n8x + n8w)     { sp = wt; dp = wtb; k = i - n8x; }
  else if (i < n8x + 2 * n8w) { sp = wr; dp = wrb; k = i - n8x - n8w; }
  else return;
  const float4 v0 = *(const float4*)(sp + (size_t)k * 8);
  const float4 v1 = *(const float4*)(sp + (size_t)k * 8 + 4);
  ushort8 o;
  o[0] = f2bf(v0.x); o[1] = f2bf(v0.y); o[2] = f2bf(v0.z); o[3] = f2bf(v0.w);
  o[4] = f2bf(v1.x); o[5] = f2bf(v1.y); o[6] = f2bf(v1.z); o[7] = f2bf(v1.w);
  *(ushort8*)(dp + (size_t)k * 8) = o;
}

// --- fused dual GEMM, SEQUENTIAL two-phase, double-buffered async-LDS --------
// out = relu(Ah @ Wt^T + bias) + Ax @ Wr^T
// r1 configuration -- measured best of this structure (40.3 us): tile 128x128,
// BK=32, 4 waves 2x2, LDS 32 KB, grid 628 + bijective XCD swizzle. Knob record:
// 64x128 = 42.6 (r4), BK=64/48KB = 48.3 (r5). 2-barrier vmcnt(0) loop plateaus
// ~40 us (m97-structure ceiling); N=512 too narrow for 8-phase 256^2. FROZEN.
__global__ __launch_bounds__(256, 3) void gemm_fused(const __bf16* __restrict__ Ah, const __bf16* __restrict__ Ax,
                                                     const __bf16* __restrict__ Wt, const __bf16* __restrict__ Wr,
                                                     const float* __restrict__ bias, float* __restrict__ out,
                                                     int M, int NB) {
  __shared__ __bf16 sA[2][128 * 32];
  __shared__ __bf16 sB[2][128 * 32];
  int tid = threadIdx.x;
  int wid = tid >> 6, lane = tid & 63;
  int wm = wid & 1, wn = wid >> 1;
  int lane15 = lane & 15, quad = lane >> 4;

  // bijective XCD swizzle (works for NB % 8 != 0): d%8 = XCD, d/8 = slot;
  // XCD x covers g in a contiguous range -> mi runs contiguous, ni = g&3.
  int d = blockIdx.x;
  int x = d & 7, s = d >> 3;
  int q = NB >> 3, r = NB & 7;
  int g = (x < r ? x * (q + 1) : r * (q + 1) + (x - r) * q) + s;
  int mi = g >> 2, ni = g & 3;
  int m0 = mi * 128, n0 = ni * 128;

  // staging: wave covers rows [wid*32, wid*32+32), 2 instrs of 16 rows each.
  // lane -> row wid*32 + lane/4 (+16), swizzled k-segment ((lane&3)-(lane>>3))&3
  int r0 = wid * 32 + (lane >> 2);
  int c0 = ((((lane & 3) - (lane >> 3)) & 3)) * 8;   // swizzled element offset
  int am0 = m0 + r0;      if (am0 >= M) am0 = M - 1;
  int am1 = m0 + r0 + 16; if (am1 >= M) am1 = M - 1;
  int bn0 = n0 + r0;                                 // N dim = 512, full tiles
  const __bf16* a00 = Ah + (size_t)am0 * FDIM + c0;  // phase-1 A
  const __bf16* a01 = Ah + (size_t)am1 * FDIM + c0;
  const __bf16* a10 = Ax + (size_t)am0 * FDIM + c0;  // phase-2 A
  const __bf16* a11 = Ax + (size_t)am1 * FDIM + c0;
  const __bf16* b00 = Wt + (size_t)bn0 * FDIM + c0;  // phase-1 B
  const __bf16* b01 = Wt + (size_t)(bn0 + 16) * FDIM + c0;
  const __bf16* b10 = Wr + (size_t)bn0 * FDIM + c0;  // phase-2 B
  const __bf16* b11 = Wr + (size_t)(bn0 + 16) * FDIM + c0;
  int loff0 = wid * 1024;          // (wid*32 rows) * 32 elems
  int loff1 = wid * 1024 + 512;    // +16 rows

  auto stage = [&](int b, const __bf16* pa0, const __bf16* pa1,
                   const __bf16* pb0, const __bf16* pb1, int kt) {
    gld16(pa0 + kt, &sA[b][loff0]); gld16(pa1 + kt, &sA[b][loff1]);
    gld16(pb0 + kt, &sB[b][loff0]); gld16(pb1 + kt, &sB[b][loff1]);
  };

  // read-side swizzled k offset: slot = (quad + (row>>1)) & 3
  int koff = ((quad + (lane15 >> 1)) & 3) * 8;

  // bias for this wave's 4 n-fragments (needed at the phase transition)
  float bn[4];
#pragma unroll
  for (int in = 0; in < 4; ++in) bn[in] = bias[n0 + wn * 64 + in * 16 + lane15];

  floatx4 acc[4][4];
  floatx4 z4; z4[0] = 0.f; z4[1] = 0.f; z4[2] = 0.f; z4[3] = 0.f;
#pragma unroll
  for (int im = 0; im < 4; ++im)
#pragma unroll
    for (int in = 0; in < 4; ++in) acc[im][in] = z4;

  stage(0, a00, a01, b00, b01, 0);
  for (int it = 0; it < 32; ++it) {
    int cb = it & 1;
    __syncthreads();                       // staging of buf cb complete; prior reads of buf 1-cb done
    int nx = it + 1;
    if (nx < 32) {
      if (nx < 16) stage(1 - cb, a00, a01, b00, b01, nx * 32);
      else         stage(1 - cb, a10, a11, b10, b11, (nx & 15) * 32);
    }
    if (it == 16) {                        // phase transition: relu(acc + bias), in registers
#pragma unroll
      for (int im = 0; im < 4; ++im)
#pragma unroll
        for (int in = 0; in < 4; ++in)
#pragma unroll
          for (int rr = 0; rr < 4; ++rr)
            acc[im][in][rr] = fmaxf(acc[im][in][rr] + bn[in], 0.f);
    }
    bf16x8 af[4], br[4];
#pragma unroll
    for (int im = 0; im < 4; ++im)
      af[im] = *(const bf16x8*)(&sA[cb][(wm * 64 + im * 16 + lane15) * 32 + koff]);
#pragma unroll
    for (int in = 0; in < 4; ++in)
      br[in] = *(const bf16x8*)(&sB[cb][(wn * 64 + in * 16 + lane15) * 32 + koff]);
#pragma unroll
    for (int im = 0; im < 4; ++im)
#pragma unroll
      for (int in = 0; in < 4; ++in)
        acc[im][in] = __builtin_amdgcn_mfma_f32_16x16x32_bf16(af[im], br[in], acc[im][in], 0, 0, 0);
  }

  // epilogue: C/D layout col=lane&15, row=quad*4+reg
#pragma unroll
  for (int im = 0; im < 4; ++im) {
#pragma unroll
    for (int in = 0; in < 4; ++in) {
#pragma unroll
      for (int rr = 0; rr < 4; ++rr) {
        int m = m0 + wm * 64 + im * 16 + quad * 4 + rr;
        int n = n0 + wn * 64 + in * 16 + lane15;
        if (m < M) out[(size_t)m * FDIM + n] = acc[im][in][rr];
      }
    }
  }
}

// ------------------------------ rowwise LayerNorm -----------------------------
__global__ __launch_bounds__(256) void ln_kernel(const float* __restrict__ pre, const float* __restrict__ gamma,
                                                 const float* __restrict__ beta, float* __restrict__ out) {
  int row = blockIdx.x, t = threadIdx.x;
  float2 v = *(const float2*)(pre + (size_t)row * FDIM + t * 2);
  float s = v.x + v.y;
  float ss = v.x * v.x + v.y * v.y;
  for (int off = 32; off; off >>= 1) { s += __shfl_down(s, off); ss += __shfl_down(ss, off); }
  __shared__ float sm[4], sm2[4];
  int wid = t >> 6, lane = t & 63;
  if (lane == 0) { sm[wid] = s; sm2[wid] = ss; }
  __syncthreads();
  if (t == 0) {
    float a = sm[0] + sm[1] + sm[2] + sm[3];
    float b = sm2[0] + sm2[1] + sm2[2] + sm2[3];
    sm[0] = a; sm2[0] = b;
  }
  __syncthreads();
  float mu = sm[0] * (1.f / FDIM);
  float var = sm2[0] * (1.f / FDIM) - mu * mu;
  float inv = rsqrtf(var + EPSv);
  float2 g  = *(const float2*)(gamma + t * 2);
  float2 bb = *(const float2*)(beta + t * 2);
  float2 o;
  o.x = (v.x - mu) * inv * g.x + bb.x;
  o.y = (v.y - mu) * inv * g.y + bb.y;
  *(float2*)(out + (size_t)row * FDIM + t * 2) = o;
}

extern "C" void kernel_launch(void* const* d_in, const int* in_sizes, int n_in,
                              void* d_out, int out_size, void* d_ws, size_t ws_size,
                              hipStream_t stream) {
  const float* x     = (const float*)d_in[0];
  const int*   ei    = (const int*)d_in[1];
  const float* ts    = (const float*)d_in[2];
  const float* W_t   = (const float*)d_in[3];
  const float* b_t   = (const float*)d_in[4];
  const float* W_r   = (const float*)d_in[5];
  const float* gamma = (const float*)d_in[6];
  const float* beta  = (const float*)d_in[7];
  const int*   gt    = (const int*)d_in[8];

  const int E = in_sizes[2];
  const int N = in_sizes[0] / FDIM;
  const int* src = ei;
  const int* dst = ei + E;
  const int totE = E + N;
  const int totEp = totE + 3 * N;   // upper bound on padded edge count
  const int nb = (N + 255) / 256;   // scan segments (N=20000 -> 79 <= 256)

  // ---- workspace carve (all regions fully rewritten every call) ----
  char* base = (char*)d_ws;
  size_t off = 0;
  auto carve = [&](size_t bytes) -> char* {
    char* r = base + off;
    off = (off + bytes + 255) & ~(size_t)255;
    return r;
  };
  unsigned long long* pc = (unsigned long long*)carve((size_t)N * 8);   // packed cnt|deg
  unsigned* cv = (unsigned*)carve((size_t)totEp * 4);                    // CSR payload (pad slots stay 0)
  size_t zero_bytes = off;                       // pc + cv zeroed (cv=0 is the pad edge: src 0, val 0)
  float* dinv  = (float*)carve((size_t)N * 4);
  int*   offs  = (int*)  carve((size_t)(N + 1) * 4);
  int*   cursor= (int*)  carve((size_t)N * 4);
  int*   bsum  = (int*)  carve((size_t)nb * 4);
  int*   bbase = (int*)  carve((size_t)nb * 4);
  float* w     = (float*)carve((size_t)totE * 4);
  unsigned short* xb  = (unsigned short*)carve((size_t)N * FDIM * 2);   // bf16(x)
  unsigned short* hba = (unsigned short*)carve((size_t)N * FDIM * 2);   // bf16 h ping
  unsigned short* hbb = (unsigned short*)carve((size_t)N * FDIM * 2);   // bf16 h pong
  unsigned short* wtb = (unsigned short*)carve((size_t)FDIM * FDIM * 2);
  unsigned short* wrb = (unsigned short*)carve((size_t)FDIM * FDIM * 2);
  float* preLN = (float*)carve((size_t)N * FDIM * 4);

  hipMemsetAsync(d_ws, 0, zero_bytes, stream);

  edge_w_deg<<<(totE + 255) / 256, 256, 0, stream>>>(src, dst, ts, gt, w, pc, E, N);
  seg_reduce<<<nb, 256, 0, stream>>>(pc, bsum, N);
  scan_bsum<<<1, 256, 0, stream>>>(bsum, bbase, offs + N, nb);
  seg_scan<<<nb, 256, 0, stream>>>(pc, bbase, offs, cursor, dinv, N);
  scatter_kernel<<<(totE + 255) / 256, 256, 0, stream>>>(src, dst, w, dinv, cursor, cv, E, N);

  // single fused cast launch: x, W_t, W_r -> bf16
  int n8x = N * FDIM / 8;
  int n8w = FDIM * FDIM / 8;
  int n8tot = n8x + 2 * n8w;
  cast_all<<<(n8tot + 255) / 256, 256, 0, stream>>>(x, W_t, W_r, xb, wtb, wrb, n8x, n8w);

  // 5 Euler steps on bf16 state; chunk = blockIdx&7 -> XCD-affine L2 residency
  int sgrid = ((N + 31) / 32) * 8;
  spmm_xcd<<<sgrid, 256, 0, stream>>>(offs, cv, xb,  hba, N);
  spmm_xcd<<<sgrid, 256, 0, stream>>>(offs, cv, hba, hbb, N);
  spmm_xcd<<<sgrid, 256, 0, stream>>>(offs, cv, hbb, hba, N);
  spmm_xcd<<<sgrid, 256, 0, stream>>>(offs, cv, hba, hbb, N);
  spmm_xcd<<<sgrid, 256, 0, stream>>>(offs, cv, hbb, hba, N);

  // fused: preLN = relu(h @ Wt^T + b_t) + x @ Wr^T  (two-phase, 1-D swizzled grid)
  int MB = (N + 127) / 128;
  int NBLK = MB * (FDIM / 128);
  gemm_fused<<<NBLK, 256, 0, stream>>>((const __bf16*)hba, (const __bf16*)xb,
                                       (const __bf16*)wtb, (const __bf16*)wrb,
                                       b_t, preLN, N, NBLK);

  ln_kernel<<<N, 256, 0, stream>>>(preLN, gamma, beta, (float*)d_out);
}